// Round 8
// baseline (146.421 us; speedup 1.0000x reference)
//
#include <hip/hip_runtime.h>
#include <hip/hip_bf16.h>
#include <stdint.h>

typedef __attribute__((ext_vector_type(8))) short short8;
typedef __attribute__((ext_vector_type(4))) float f32x4;

#define L2E 1.44269504f
#define FN  131072              // elements per f-array: H*B*N = 8*32*512

__device__ __forceinline__ short f2bf(float f) {
    unsigned u = __builtin_bit_cast(unsigned, f);
    return (short)((u + 0x8000u) >> 16);   // round-half-up to bf16
}
__device__ __forceinline__ short f2bf_rn(float f) {    // compiler RNE cast
    __hip_bfloat16 h = __float2bfloat16(f);            // -> v_cvt_pk_bf16_f32
    return __builtin_bit_cast(short, h);
}
__device__ __forceinline__ float bf2f(short s) {
    unsigned u = ((unsigned)(unsigned short)s) << 16;
    return __builtin_bit_cast(float, u);
}

// async global->LDS, 16B per lane; LDS dest = wave-uniform base + lane*16
__device__ __forceinline__ void gld16(void* l, const void* g) {
    __builtin_amdgcn_global_load_lds(
        (const __attribute__((address_space(1))) unsigned*)g,
        (__attribute__((address_space(3))) unsigned*)l, 16, 0, 0);
}

// Hardened pipeline sync helpers (raw s_barrier does NOT order memory):
#define PIPE_OPEN()  do { __builtin_amdgcn_s_barrier();                        \
                          __builtin_amdgcn_sched_barrier(0);                   \
                          asm volatile("" ::: "memory"); } while (0)
#define PIPE_CLOSE() do { asm volatile("s_waitcnt lgkmcnt(0)" ::: "memory");   \
                          __builtin_amdgcn_sched_barrier(0);                   \
                          __builtin_amdgcn_s_barrier(); } while (0)

// ---------------------------------------------------------------------------
// Kernel 1: transpose + fp32->bf16 convert W -> BT.
// ---------------------------------------------------------------------------
__global__ void wtrans_kernel(const float* __restrict__ W0, const float* __restrict__ W1,
                              short* __restrict__ BT0, short* __restrict__ BT1) {
    int idx = blockIdx.x * 256 + threadIdx.x;
    if (idx < 8 * 128 * 64) {
        int h = idx >> 13;
        int k = (idx >> 6) & 127;
        int dd = idx & 63;
        BT0[(h * 64 + dd) * 128 + k] = f2bf(W0[idx]);
    } else {
        int j = idx - 8 * 128 * 64;
        int h = j >> 15;
        int k = (j >> 6) & 511;
        int dd = j & 63;
        BT1[(h * 64 + dd) * 512 + k] = f2bf(W1[j]);
    }
}

// ---------------------------------------------------------------------------
// Kernel 2: GEMM  C(16384 x 512) = A(16384 x K) @ BT(512 x K)^T, bf16 MFMA.
// 1D grid, XCD-aware decode; bf16-A path pipelined (counted vmcnt + hardened
// barriers); fp32-A path legacy __syncthreads. (unchanged from round 4)
// ---------------------------------------------------------------------------
template <typename AT>
__global__ __launch_bounds__(256, 2)
void gemm_kernel(const AT* __restrict__ A, const short* __restrict__ BT,
                 short* __restrict__ fts, int K,
                 const float* __restrict__ a1w, const float* __restrict__ a1b,
                 const float* __restrict__ a2w, const float* __restrict__ a2b,
                 float* __restrict__ fbuf) {
    __shared__ __align__(16) short As[2][128 * 64];   // 32 KB
    __shared__ __align__(16) short Bs[2][128 * 64];   // 32 KB

    const int tid  = threadIdx.x;
    const int lane = tid & 63;
    const int w    = tid >> 6;
    const int wr   = w >> 1, wc = w & 1;
    const int quad = lane >> 4, l15 = lane & 15;

    // XCD-aware decode: id bits [8:5]=g, [4:3]=k(n-block), [2:0]=x.
    // by = g*8+x; same-by blocks differ by 8 -> same XCD. Bijective.
    const int id = blockIdx.x;
    const int bx = (id >> 3) & 3;
    const int by = ((id >> 5) << 3) + (id & 7);
    const int m0 = by * 128;
    const int n0 = bx * 128;

    // async-staging lane map: 8 rows x 8 chunks per instr
    const int rl   = lane >> 3;        // row_local 0..7
    const int cpos = lane & 7;         // physical LDS chunk
    const int kcl  = cpos ^ rl;        // global chunk to fetch ((row&7)==rl)

    f32x4 acc[4][4];
    for (int i = 0; i < 4; ++i)
        for (int j = 0; j < 4; ++j) { f32x4 z = {0.f, 0.f, 0.f, 0.f}; acc[i][j] = z; }

    const int nkb = K >> 6;

    if constexpr (sizeof(AT) == 4) {
        // ---------------- legacy loop: fp32 A (K=128, 2 k-steps) ----------
        for (int kb = 0; kb < nkb; ++kb) {
            __syncthreads();
            for (int i = 0; i < 8; ++i) {      // fp32 A: manual convert-staging
                int id2 = tid + i * 256;
                int row = id2 >> 4, q = id2 & 15;  // q: 4-float subchunk
                int c = q >> 1, half = q & 1;
                float4 v = *(const float4*)((const float*)A + (size_t)(m0 + row) * K + kb * 64 + q * 4);
                ushort4 p;
                p.x = (unsigned short)f2bf(v.x);
                p.y = (unsigned short)f2bf(v.y);
                p.z = (unsigned short)f2bf(v.z);
                p.w = (unsigned short)f2bf(v.w);
                int swz = c ^ (row & 7);
                *(ushort4*)(As[0] + row * 64 + swz * 8 + half * 4) = p;
            }
            for (int i = 0; i < 4; ++i) {      // B bf16 async
                int rowb = w * 32 + i * 8;
                gld16(Bs[0] + rowb * 64,
                      BT + (size_t)(n0 + rowb + rl) * K + kb * 64 + kcl * 8);
            }
            __syncthreads();
            short8 af[2][4], bf[2][4];
            for (int ks = 0; ks < 2; ++ks) {
                for (int mf = 0; mf < 4; ++mf) {
                    int row = wr * 64 + mf * 16 + l15;
                    af[ks][mf] = *(const short8*)(As[0] + row * 64 + (((ks * 4 + quad) ^ (row & 7)) << 3));
                }
                for (int nf = 0; nf < 4; ++nf) {
                    int row = wc * 64 + nf * 16 + l15;
                    bf[ks][nf] = *(const short8*)(Bs[0] + row * 64 + (((ks * 4 + quad) ^ (row & 7)) << 3));
                }
            }
            for (int ks = 0; ks < 2; ++ks)
                for (int mf = 0; mf < 4; ++mf)
                    for (int nf = 0; nf < 4; ++nf)
                        acc[mf][nf] = __builtin_amdgcn_mfma_f32_16x16x32_bf16(af[ks][mf], bf[ks][nf], acc[mf][nf], 0, 0, 0);
        }
    } else {
        // ---------------- pipelined loop: bf16 A (K=512, 8 k-steps) -------
        auto stageAB = [&](int kb, int bufi) {
#pragma unroll
            for (int i = 0; i < 4; ++i) {
                int rowb = w * 32 + i * 8;
                gld16(As[bufi] + rowb * 64,
                      (const short*)A + (size_t)(m0 + rowb + rl) * K + kb * 64 + kcl * 8);
            }
#pragma unroll
            for (int i = 0; i < 4; ++i) {
                int rowb = w * 32 + i * 8;
                gld16(Bs[bufi] + rowb * 64,
                      BT + (size_t)(n0 + rowb + rl) * K + kb * 64 + kcl * 8);
            }
        };
        stageAB(0, 0);
        if (nkb > 1) stageAB(1, 1);
        for (int kb = 0; kb < nkb; ++kb) {
            // own stage(kb) done; stage(kb+1)'s 8 gld16 stay in flight
            if (kb + 1 < nkb) asm volatile("s_waitcnt vmcnt(8)" ::: "memory");
            else              asm volatile("s_waitcnt vmcnt(0)" ::: "memory");
            PIPE_OPEN();                     // all waves' stage(kb) done; reads pinned below
            const short* as = As[kb & 1];
            const short* bs = Bs[kb & 1];
            short8 af[2][4], bf[2][4];
            for (int ks = 0; ks < 2; ++ks) {
                for (int mf = 0; mf < 4; ++mf) {
                    int row = wr * 64 + mf * 16 + l15;
                    af[ks][mf] = *(const short8*)(as + row * 64 + (((ks * 4 + quad) ^ (row & 7)) << 3));
                }
                for (int nf = 0; nf < 4; ++nf) {
                    int row = wc * 64 + nf * 16 + l15;
                    bf[ks][nf] = *(const short8*)(bs + row * 64 + (((ks * 4 + quad) ^ (row & 7)) << 3));
                }
            }
            for (int ks = 0; ks < 2; ++ks)
                for (int mf = 0; mf < 4; ++mf)
                    for (int nf = 0; nf < 4; ++nf)
                        acc[mf][nf] = __builtin_amdgcn_mfma_f32_16x16x32_bf16(af[ks][mf], bf[ks][nf], acc[mf][nf], 0, 0, 0);
            PIPE_CLOSE();                    // reads drained; safe to restage
            if (kb + 2 < nkb) stageAB(kb + 2, kb & 1);
        }
    }

    // ---- epilogue A: transposed fts store
    for (int nf = 0; nf < 4; ++nf) {
        int col = n0 + wc * 64 + nf * 16 + l15;
        int h = col >> 6, dd = col & 63;
        for (int mf = 0; mf < 4; ++mf) {
            int m = m0 + wr * 64 + mf * 16 + quad * 4;
            int b = m >> 9, n = m & 511;
            ushort4 pk;
            pk.x = (unsigned short)f2bf(acc[mf][nf][0]);
            pk.y = (unsigned short)f2bf(acc[mf][nf][1]);
            pk.z = (unsigned short)f2bf(acc[mf][nf][2]);
            pk.w = (unsigned short)f2bf(acc[mf][nf][3]);
            *(ushort4*)(fts + (size_t)((h * 32 + b) * 64 + dd) * 512 + n) = pk;
        }
    }

    // ---- epilogue B: P/Q exp factors from fp32 acc. head = n0/64 + wc.
    {
        const int head = (n0 >> 6) + wc;
        float w1[4], w2[4];
        for (int nf = 0; nf < 4; ++nf) {
            w1[nf] = a1w[head * 64 + nf * 16 + l15];
            w2[nf] = a2w[head * 64 + nf * 16 + l15];
        }
        const float b1 = a1b[head], b2 = a2b[head];
        const int rsel = l15 & 3;
        for (int mf = 0; mf < 4; ++mf) {
            float g1[4], g2[4];
            for (int r = 0; r < 4; ++r) {
                float s1 = 0.f, s2 = 0.f;
                for (int nf = 0; nf < 4; ++nf) {
                    s1 += acc[mf][nf][r] * w1[nf];
                    s2 += acc[mf][nf][r] * w2[nf];
                }
                for (int m = 1; m < 16; m <<= 1) {
                    s1 += __shfl_xor(s1, m, 64);
                    s2 += __shfl_xor(s2, m, 64);
                }
                g1[r] = s1; g2[r] = s2;
            }
            float v1 = rsel == 0 ? g1[0] : rsel == 1 ? g1[1] : rsel == 2 ? g1[2] : g1[3];
            float v2 = rsel == 0 ? g2[0] : rsel == 1 ? g2[1] : rsel == 2 ? g2[2] : g2[3];
            if (l15 < 4) {
                int m = m0 + wr * 64 + mf * 16 + quad * 4 + rsel;
                int b = m >> 9, i = m & 511;
                int fi = (head * 32 + b) * 512 + i;
                float f1 = v1 + b1, f2 = v2 + b2;
                fbuf[0 * FN + fi] = __builtin_amdgcn_exp2f(f1 * L2E);
                fbuf[1 * FN + fi] = __builtin_amdgcn_exp2f(f1 * (0.01f * L2E));
                fbuf[2 * FN + fi] = __builtin_amdgcn_exp2f(f2 * L2E);
                fbuf[3 * FN + fi] = __builtin_amdgcn_exp2f(f2 * (0.01f * L2E));
            }
        }
    }
}

// ---------------------------------------------------------------------------
// Kernel 3: fused GAT attention. One block = (h, b, 256-row half).
//   e~(i,j) = max(P2_j, R_i*Q2_j), R_i=Q1_i/P1_i (row-scale invariant form)
//   O[i,:] = sum_j e~ * fts[j,:];  L[i] = sum_j e~;  out = elu(O/L + fts[i,:])
// BARRIER-FREE compute (round 8): R6/R7 showed attn is bound by neither
// staging latency nor VALU throughput -- the 16 lockstep barrier rendezvous
// per block were the residual cost. The 64KB slab fits in LDS whole: stage
// ALL of it (+pq) up front (17 gld16/wave), ONE vmcnt(0) + ONE barrier,
// then zero barriers -- compiler schedules ds_reads across all 8 chunks.
// 256 rows/block (grid 512, 2 blocks/CU exact, 68KB LDS), 4 rt/wave ->
// per-CU LDS read traffic halves. Residual read now from LDS, not global.
// Same (tc, jb, k) accumulation order per row -> bit-identical to round 7.
// ---------------------------------------------------------------------------
template <typename OutT>
__global__ __launch_bounds__(256, 2)
void attn_kernel(const short* __restrict__ fts, const float* __restrict__ fbuf,
                 OutT* __restrict__ out) {
    __shared__ __align__(16) short fts_s[8][64 * 64];  // whole 64KB slab, 8KB chunks
    __shared__ __align__(16) float p2_s[512];          // 2 KB
    __shared__ __align__(16) float q2_s[512];          // 2 KB

    const int tid  = threadIdx.x;
    const int lane = tid & 63, w = tid >> 6;
    const int quad = lane >> 4, l15 = lane & 15;
    const int bx   = blockIdx.x;
    const int half = bx >> 8;              // 0..1
    const int slab = bx & 255;             // h*32+b, same-XCD for both halves
    const int h    = slab >> 5;
    const int b    = slab & 31;
    const int r0   = half * 256;
    const size_t fbase = (size_t)(slab * 64) * 512;
    const int fidx = slab * 512;

    // staging lane map: each gld16 covers 8 d-rows x 8 slots of 16B (64 n)
    const int srow = lane >> 3;            // d-row within instr group 0..7
    const int spc  = lane & 7;             // physical LDS 16B slot

    f32x4 acc[4][4], accL[4];
#pragma unroll
    for (int i = 0; i < 4; ++i) {
        f32x4 z = {0.f, 0.f, 0.f, 0.f};
        accL[i] = z;
        for (int j = 0; j < 4; ++j) acc[i][j] = z;
    }
    short8 onesv;
    for (int t = 0; t < 8; ++t) onesv[t] = (short)0x3F80;   // bf16 1.0

    float Rr[4];                           // R_i = Q1_i / P1_i per rt
#pragma unroll
    for (int rt = 0; rt < 4; ++rt) {
        int i = fidx + r0 + w * 64 + rt * 16 + l15;
        float P1 = fbuf[i];
        float Q1 = fbuf[1 * FN + i];
        Rr[rt] = Q1 * __builtin_amdgcn_rcpf(P1);
    }

    const float* p2g = fbuf + 2 * FN + fidx;
    const float* q2g = fbuf + 3 * FN + fidx;

    // ---- issue p/q staging (1 gld16 per wave)
    if (w < 2) gld16(p2_s + w * 256, p2g + w * 256 + lane * 4);
    else       gld16(q2_s + (w - 2) * 256, q2g + (w - 2) * 256 + lane * 4);

    // ---- stage the WHOLE slab: 8 chunks x 2 gld16/wave = 16 gld16/wave.
    //      LDS slot spc holds global 16B-chunk spc^(d&7) (source pre-swizzle).
#pragma unroll
    for (int tc = 0; tc < 8; ++tc) {
#pragma unroll
        for (int i = 0; i < 2; ++i) {
            int d0 = w * 16 + i * 8;       // multiple of 8 -> d&7 == srow
            int d  = d0 + srow;
            gld16(&fts_s[tc][0] + d0 * 64,
                  fts + fbase + (size_t)d * 512 + tc * 64 + ((spc ^ srow) << 3));
        }
    }

    // ---- single rendezvous: all staging complete, then barrier-free
    asm volatile("s_waitcnt vmcnt(0)" ::: "memory");
    PIPE_OPEN();

#pragma unroll
    for (int tc = 0; tc < 8; ++tc) {
        const short* buf = &fts_s[tc][0];
#pragma unroll
        for (int jb = 0; jb < 2; ++jb) {       // 32 j per step
            short8 bfr[4];
#pragma unroll
            for (int nf = 0; nf < 4; ++nf) {
                int col = nf * 16 + l15;
                bfr[nf] = *(const short8*)(buf + col * 64 + (((jb * 4 + quad) ^ (col & 7)) << 3));
            }
            int o = tc * 64 + jb * 32 + quad * 8;
            f32x4 pa = *(const f32x4*)(p2_s + o), pb = *(const f32x4*)(p2_s + o + 4);
            f32x4 qa = *(const f32x4*)(q2_s + o), qb = *(const f32x4*)(q2_s + o + 4);
            float p2v[8] = {pa[0], pa[1], pa[2], pa[3], pb[0], pb[1], pb[2], pb[3]};
            float q2v[8] = {qa[0], qa[1], qa[2], qa[3], qb[0], qb[1], qb[2], qb[3]};

#pragma unroll
            for (int rt = 0; rt < 4; ++rt) {   // E-frag in A-layout: m=l15, k=quad*8+t
                const float R = Rr[rt];
                short8 ef;
#pragma unroll
                for (int t = 0; t < 8; ++t)
                    ef[t] = f2bf_rn(fmaxf(p2v[t], R * q2v[t]));
                for (int nf = 0; nf < 4; ++nf)
                    acc[rt][nf] = __builtin_amdgcn_mfma_f32_16x16x32_bf16(ef, bfr[nf], acc[rt][nf], 0, 0, 0);
                accL[rt] = __builtin_amdgcn_mfma_f32_16x16x32_bf16(ef, onesv, accL[rt], 0, 0, 0);
            }
        }
    }

    // ---- epilogue: normalize, residual (from LDS slab), ELU, store
#pragma unroll
    for (int rt = 0; rt < 4; ++rt) {
        float rinv[4];
        for (int r = 0; r < 4; ++r) rinv[r] = __builtin_amdgcn_rcpf(accL[rt][r]);
        int i0 = r0 + w * 64 + rt * 16 + quad * 4;
        int nn = i0 & 511;                  // n index within slab (=i0, r0<512)
        int tcC = nn >> 6, nl = nn & 63;
#pragma unroll
        for (int nf = 0; nf < 4; ++nf) {
            int col = nf * 16 + l15;
            const short* rbase = &fts_s[tcC][0] + col * 64 + (((nl >> 3) ^ (col & 7)) << 3) + (nl & 7);
            ushort4 res = *(const ushort4*)rbase;
            unsigned short rr[4] = {res.x, res.y, res.z, res.w};
            for (int r = 0; r < 4; ++r) {
                float val = acc[rt][nf][r] * rinv[r] + bf2f((short)rr[r]);
                if (val < 0.f) val = __builtin_amdgcn_exp2f(val * L2E) - 1.f;  // elu
                size_t oidx = (size_t)(b * 512 + i0 + r) * 512 + h * 64 + col;
                if constexpr (sizeof(OutT) == 4) out[oidx] = val;
                else                             out[oidx] = f2bf(val);
            }
        }
    }
}

// ---------------------------------------------------------------------------
extern "C" void kernel_launch(void* const* d_in, const int* in_sizes, int n_in,
                              void* d_out, int out_size, void* d_ws, size_t ws_size,
                              hipStream_t stream) {
    const float* x   = (const float*)d_in[0];   // (32,512,128) f32
    const float* W0  = (const float*)d_in[1];   // (8,128,64)
    const float* W1  = (const float*)d_in[2];   // (8,512,64)
    const float* a1w = (const float*)d_in[3];   // (2,8,64)
    const float* a1b = (const float*)d_in[4];   // (2,8)
    const float* a2w = (const float*)d_in[5];   // (2,8,64)
    const float* a2b = (const float*)d_in[6];   // (2,8)
    float* out = (float*)d_out;                 // (32,512,512) f32

    char* ws = (char*)d_ws;
    short* BT0  = (short*)(ws);                 // 512x128 bf16   (131072 B)
    short* BT1  = (short*)(ws + 131072);        // 512x512 bf16   (524288 B)
    float* fbuf = (float*)(ws + 655360);        // 4 x 131072 f32 (2097152 B)
    short* fts  = (short*)(ws + 2752512);       // (8,32,64,512) bf16 (16.78 MB)
    short* hbuf = (short*)d_out;                // bf16 hidden in d_out (overwritten later)

    wtrans_kernel<<<1280, 256, 0, stream>>>(W0, W1, BT0, BT1);

    // stack 0
    gemm_kernel<float><<<512, 256, 0, stream>>>(x, BT0, fts, 128,
                                                a1w, a1b, a2w, a2b, fbuf);
    attn_kernel<short><<<512, 256, 0, stream>>>(fts, fbuf, hbuf);

    // stack 1
    gemm_kernel<short><<<512, 256, 0, stream>>>(hbuf, BT1, fts, 512,
                                                a1w + 512, a1b + 8, a2w + 512, a2b + 8, fbuf);
    attn_kernel<float><<<512, 256, 0, stream>>>(fts, fbuf, out);
}

// Round 9
// 145.687 us; speedup vs baseline: 1.0050x; 1.0050x over previous
//
#include <hip/hip_runtime.h>
#include <hip/hip_bf16.h>
#include <stdint.h>

typedef __attribute__((ext_vector_type(8))) short short8;
typedef __attribute__((ext_vector_type(4))) float f32x4;

#define L2E 1.44269504f
#define FN  131072              // elements per f-array: H*B*N = 8*32*512

__device__ __forceinline__ short f2bf(float f) {
    unsigned u = __builtin_bit_cast(unsigned, f);
    return (short)((u + 0x8000u) >> 16);   // round-half-up to bf16
}
__device__ __forceinline__ short f2bf_rn(float f) {    // compiler RNE cast
    __hip_bfloat16 h = __float2bfloat16(f);            // -> v_cvt_pk_bf16_f32
    return __builtin_bit_cast(short, h);
}
__device__ __forceinline__ float bf2f(short s) {
    unsigned u = ((unsigned)(unsigned short)s) << 16;
    return __builtin_bit_cast(float, u);
}

// async global->LDS, 16B per lane; LDS dest = wave-uniform base + lane*16
__device__ __forceinline__ void gld16(void* l, const void* g) {
    __builtin_amdgcn_global_load_lds(
        (const __attribute__((address_space(1))) unsigned*)g,
        (__attribute__((address_space(3))) unsigned*)l, 16, 0, 0);
}

// Hardened pipeline sync helpers (raw s_barrier does NOT order memory):
//  PIPE_OPEN : after the vmcnt-wait + barrier, pin all reads BELOW the
//              barrier (cross-wave staging only guaranteed complete there).
//  PIPE_CLOSE: drain own LDS reads (lgkmcnt) and pin them ABOVE the barrier
//              before any wave restages into the buffer just read.
#define PIPE_OPEN()  do { __builtin_amdgcn_s_barrier();                        \
                          __builtin_amdgcn_sched_barrier(0);                   \
                          asm volatile("" ::: "memory"); } while (0)
#define PIPE_CLOSE() do { asm volatile("s_waitcnt lgkmcnt(0)" ::: "memory");   \
                          __builtin_amdgcn_sched_barrier(0);                   \
                          __builtin_amdgcn_s_barrier(); } while (0)

// ---------------------------------------------------------------------------
// Kernel 1: transpose + fp32->bf16 convert W -> BT.
// ---------------------------------------------------------------------------
__global__ void wtrans_kernel(const float* __restrict__ W0, const float* __restrict__ W1,
                              short* __restrict__ BT0, short* __restrict__ BT1) {
    int idx = blockIdx.x * 256 + threadIdx.x;
    if (idx < 8 * 128 * 64) {
        int h = idx >> 13;
        int k = (idx >> 6) & 127;
        int dd = idx & 63;
        BT0[(h * 64 + dd) * 128 + k] = f2bf(W0[idx]);
    } else {
        int j = idx - 8 * 128 * 64;
        int h = j >> 15;
        int k = (j >> 6) & 511;
        int dd = j & 63;
        BT1[(h * 64 + dd) * 512 + k] = f2bf(W1[j]);
    }
}

// ---------------------------------------------------------------------------
// Kernel 2: GEMM  C(16384 x 512) = A(16384 x K) @ BT(512 x K)^T, bf16 MFMA.
// 1D grid, XCD-aware decode; bf16-A path pipelined (counted vmcnt + hardened
// barriers); fp32-A path legacy __syncthreads. Round 9: T5 s_setprio(1)
// around the MFMA nest in the pipelined loop (wave-role arbitration).
// ---------------------------------------------------------------------------
template <typename AT>
__global__ __launch_bounds__(256, 2)
void gemm_kernel(const AT* __restrict__ A, const short* __restrict__ BT,
                 short* __restrict__ fts, int K,
                 const float* __restrict__ a1w, const float* __restrict__ a1b,
                 const float* __restrict__ a2w, const float* __restrict__ a2b,
                 float* __restrict__ fbuf) {
    __shared__ __align__(16) short As[2][128 * 64];   // 32 KB
    __shared__ __align__(16) short Bs[2][128 * 64];   // 32 KB

    const int tid  = threadIdx.x;
    const int lane = tid & 63;
    const int w    = tid >> 6;
    const int wr   = w >> 1, wc = w & 1;
    const int quad = lane >> 4, l15 = lane & 15;

    // XCD-aware decode: id bits [8:5]=g, [4:3]=k(n-block), [2:0]=x.
    // by = g*8+x; same-by blocks differ by 8 -> same XCD. Bijective.
    const int id = blockIdx.x;
    const int bx = (id >> 3) & 3;
    const int by = ((id >> 5) << 3) + (id & 7);
    const int m0 = by * 128;
    const int n0 = bx * 128;

    // async-staging lane map: 8 rows x 8 chunks per instr
    const int rl   = lane >> 3;        // row_local 0..7
    const int cpos = lane & 7;         // physical LDS chunk
    const int kcl  = cpos ^ rl;        // global chunk to fetch ((row&7)==rl)

    f32x4 acc[4][4];
    for (int i = 0; i < 4; ++i)
        for (int j = 0; j < 4; ++j) { f32x4 z = {0.f, 0.f, 0.f, 0.f}; acc[i][j] = z; }

    const int nkb = K >> 6;

    if constexpr (sizeof(AT) == 4) {
        // ---------------- legacy loop: fp32 A (K=128, 2 k-steps) ----------
        for (int kb = 0; kb < nkb; ++kb) {
            __syncthreads();
            for (int i = 0; i < 8; ++i) {      // fp32 A: manual convert-staging
                int id2 = tid + i * 256;
                int row = id2 >> 4, q = id2 & 15;  // q: 4-float subchunk
                int c = q >> 1, half = q & 1;
                float4 v = *(const float4*)((const float*)A + (size_t)(m0 + row) * K + kb * 64 + q * 4);
                ushort4 p;
                p.x = (unsigned short)f2bf(v.x);
                p.y = (unsigned short)f2bf(v.y);
                p.z = (unsigned short)f2bf(v.z);
                p.w = (unsigned short)f2bf(v.w);
                int swz = c ^ (row & 7);
                *(ushort4*)(As[0] + row * 64 + swz * 8 + half * 4) = p;
            }
            for (int i = 0; i < 4; ++i) {      // B bf16 async
                int rowb = w * 32 + i * 8;
                gld16(Bs[0] + rowb * 64,
                      BT + (size_t)(n0 + rowb + rl) * K + kb * 64 + kcl * 8);
            }
            __syncthreads();
            short8 af[2][4], bf[2][4];
            for (int ks = 0; ks < 2; ++ks) {
                for (int mf = 0; mf < 4; ++mf) {
                    int row = wr * 64 + mf * 16 + l15;
                    af[ks][mf] = *(const short8*)(As[0] + row * 64 + (((ks * 4 + quad) ^ (row & 7)) << 3));
                }
                for (int nf = 0; nf < 4; ++nf) {
                    int row = wc * 64 + nf * 16 + l15;
                    bf[ks][nf] = *(const short8*)(Bs[0] + row * 64 + (((ks * 4 + quad) ^ (row & 7)) << 3));
                }
            }
            for (int ks = 0; ks < 2; ++ks)
                for (int mf = 0; mf < 4; ++mf)
                    for (int nf = 0; nf < 4; ++nf)
                        acc[mf][nf] = __builtin_amdgcn_mfma_f32_16x16x32_bf16(af[ks][mf], bf[ks][nf], acc[mf][nf], 0, 0, 0);
        }
    } else {
        // ---------------- pipelined loop: bf16 A (K=512, 8 k-steps) -------
        auto stageAB = [&](int kb, int bufi) {
#pragma unroll
            for (int i = 0; i < 4; ++i) {
                int rowb = w * 32 + i * 8;
                gld16(As[bufi] + rowb * 64,
                      (const short*)A + (size_t)(m0 + rowb + rl) * K + kb * 64 + kcl * 8);
            }
#pragma unroll
            for (int i = 0; i < 4; ++i) {
                int rowb = w * 32 + i * 8;
                gld16(Bs[bufi] + rowb * 64,
                      BT + (size_t)(n0 + rowb + rl) * K + kb * 64 + kcl * 8);
            }
        };
        stageAB(0, 0);
        if (nkb > 1) stageAB(1, 1);
        for (int kb = 0; kb < nkb; ++kb) {
            // own stage(kb) done; stage(kb+1)'s 8 gld16 stay in flight
            if (kb + 1 < nkb) asm volatile("s_waitcnt vmcnt(8)" ::: "memory");
            else              asm volatile("s_waitcnt vmcnt(0)" ::: "memory");
            PIPE_OPEN();                     // all waves' stage(kb) done; reads pinned below
            const short* as = As[kb & 1];
            const short* bs = Bs[kb & 1];
            short8 af[2][4], bf[2][4];
            for (int ks = 0; ks < 2; ++ks) {
                for (int mf = 0; mf < 4; ++mf) {
                    int row = wr * 64 + mf * 16 + l15;
                    af[ks][mf] = *(const short8*)(as + row * 64 + (((ks * 4 + quad) ^ (row & 7)) << 3));
                }
                for (int nf = 0; nf < 4; ++nf) {
                    int row = wc * 64 + nf * 16 + l15;
                    bf[ks][nf] = *(const short8*)(bs + row * 64 + (((ks * 4 + quad) ^ (row & 7)) << 3));
                }
            }
            __builtin_amdgcn_s_setprio(1);   // T5: favor MFMA-issuing wave
            for (int ks = 0; ks < 2; ++ks)
                for (int mf = 0; mf < 4; ++mf)
                    for (int nf = 0; nf < 4; ++nf)
                        acc[mf][nf] = __builtin_amdgcn_mfma_f32_16x16x32_bf16(af[ks][mf], bf[ks][nf], acc[mf][nf], 0, 0, 0);
            __builtin_amdgcn_s_setprio(0);
            PIPE_CLOSE();                    // reads drained; safe to restage
            if (kb + 2 < nkb) stageAB(kb + 2, kb & 1);
        }
    }

    // ---- epilogue A: transposed fts store
    for (int nf = 0; nf < 4; ++nf) {
        int col = n0 + wc * 64 + nf * 16 + l15;
        int h = col >> 6, dd = col & 63;
        for (int mf = 0; mf < 4; ++mf) {
            int m = m0 + wr * 64 + mf * 16 + quad * 4;
            int b = m >> 9, n = m & 511;
            ushort4 pk;
            pk.x = (unsigned short)f2bf(acc[mf][nf][0]);
            pk.y = (unsigned short)f2bf(acc[mf][nf][1]);
            pk.z = (unsigned short)f2bf(acc[mf][nf][2]);
            pk.w = (unsigned short)f2bf(acc[mf][nf][3]);
            *(ushort4*)(fts + (size_t)((h * 32 + b) * 64 + dd) * 512 + n) = pk;
        }
    }

    // ---- epilogue B: P/Q exp factors from fp32 acc. head = n0/64 + wc.
    {
        const int head = (n0 >> 6) + wc;
        float w1[4], w2[4];
        for (int nf = 0; nf < 4; ++nf) {
            w1[nf] = a1w[head * 64 + nf * 16 + l15];
            w2[nf] = a2w[head * 64 + nf * 16 + l15];
        }
        const float b1 = a1b[head], b2 = a2b[head];
        const int rsel = l15 & 3;
        for (int mf = 0; mf < 4; ++mf) {
            float g1[4], g2[4];
            for (int r = 0; r < 4; ++r) {
                float s1 = 0.f, s2 = 0.f;
                for (int nf = 0; nf < 4; ++nf) {
                    s1 += acc[mf][nf][r] * w1[nf];
                    s2 += acc[mf][nf][r] * w2[nf];
                }
                for (int m = 1; m < 16; m <<= 1) {
                    s1 += __shfl_xor(s1, m, 64);
                    s2 += __shfl_xor(s2, m, 64);
                }
                g1[r] = s1; g2[r] = s2;
            }
            float v1 = rsel == 0 ? g1[0] : rsel == 1 ? g1[1] : rsel == 2 ? g1[2] : g1[3];
            float v2 = rsel == 0 ? g2[0] : rsel == 1 ? g2[1] : rsel == 2 ? g2[2] : g2[3];
            if (l15 < 4) {
                int m = m0 + wr * 64 + mf * 16 + quad * 4 + rsel;
                int b = m >> 9, i = m & 511;
                int fi = (head * 32 + b) * 512 + i;
                float f1 = v1 + b1, f2 = v2 + b2;
                fbuf[0 * FN + fi] = __builtin_amdgcn_exp2f(f1 * L2E);
                fbuf[1 * FN + fi] = __builtin_amdgcn_exp2f(f1 * (0.01f * L2E));
                fbuf[2 * FN + fi] = __builtin_amdgcn_exp2f(f2 * L2E);
                fbuf[3 * FN + fi] = __builtin_amdgcn_exp2f(f2 * (0.01f * L2E));
            }
        }
    }
}

// ---------------------------------------------------------------------------
// Kernel 3: fused GAT attention. One block = (h, b, 128-row quarter).
//   e~(i,j) = max(P2_j, R_i*Q2_j), R_i=Q1_i/P1_i (row-scale invariant form)
//   O[i,:] = sum_j e~ * fts[j,:];  L[i] = sum_j e~;  out = elu(O/L + fts[i,:])
// Base = round 7 (best, 144.70): 8x8KB chunks, 4-buffer ring, depth-3
// prefetch, counted vmcnt + hardened barriers, thin E-pack.
// Round 9 single change: T5 s_setprio(1) around the E-pack+MFMA cluster.
// With 4 blocks/CU at different pipeline phases, staging-issuing waves and
// MFMA-entering waves compete for issue; priority favors the MFMA feeders.
// ---------------------------------------------------------------------------
template <typename OutT>
__global__ __launch_bounds__(256, 4)
void attn_kernel(const short* __restrict__ fts, const float* __restrict__ fbuf,
                 OutT* __restrict__ out) {
    __shared__ __align__(16) short fbs[4][64 * 64];  // 4 x 8KB chunk ring
    __shared__ __align__(16) float p2_s[512];        // 2 KB
    __shared__ __align__(16) float q2_s[512];        // 2 KB

    const int tid  = threadIdx.x;
    const int lane = tid & 63, w = tid >> 6;
    const int quad = lane >> 4, l15 = lane & 15;
    const int bx   = blockIdx.x;
    const int quarter = bx >> 8;           // 0..3
    const int slab = bx & 255;             // h*32+b, same-XCD for all 4 quarters
    const int h    = slab >> 5;
    const int b    = slab & 31;
    const int r0   = quarter * 128;
    const size_t fbase = (size_t)(slab * 64) * 512;
    const int fidx = slab * 512;

    // staging lane map: each gld16 covers 8 d-rows x 8 slots of 16B (64 n)
    const int srow = lane >> 3;            // d-row within instr group 0..7
    const int spc  = lane & 7;             // physical LDS 16B slot

    f32x4 acc[2][4], accL[2];
    for (int i = 0; i < 2; ++i) {
        f32x4 z = {0.f, 0.f, 0.f, 0.f};
        accL[i] = z;
        for (int j = 0; j < 4; ++j) acc[i][j] = z;
    }
    short8 onesv;
    for (int t = 0; t < 8; ++t) onesv[t] = (short)0x3F80;   // bf16 1.0

    float Rr[2];                           // R_i = Q1_i / P1_i per rt
    for (int rt = 0; rt < 2; ++rt) {
        int i = fidx + r0 + w * 32 + rt * 16 + l15;
        float P1 = fbuf[i];
        float Q1 = fbuf[1 * FN + i];
        Rr[rt] = Q1 * __builtin_amdgcn_rcpf(P1);
    }

    const float* p2g = fbuf + 2 * FN + fidx;
    const float* q2g = fbuf + 3 * FN + fidx;

    // ---- issue p/q staging (1 gld16 per wave -> uniform vmcnt counts)
    if (w < 2) gld16(p2_s + w * 256, p2g + w * 256 + lane * 4);
    else       gld16(q2_s + (w - 2) * 256, q2g + (w - 2) * 256 + lane * 4);

    // ---- chunk staging: 2 gld16/thread-wave covers 16 d-rows x 64 n.
    //      LDS slot spc holds global 16B-chunk spc^(d&7) (source pre-swizzle,
    //      LDS linear; reads apply the same XOR).
    auto stage = [&](int tc, short* buf) {
#pragma unroll
        for (int i = 0; i < 2; ++i) {
            int d0 = w * 16 + i * 8;       // multiple of 8 -> d&7 == srow
            int d  = d0 + srow;
            gld16(buf + d0 * 64,
                  fts + fbase + (size_t)d * 512 + tc * 64 + ((spc ^ srow) << 3));
        }
    };
    stage(0, fbs[0]);
    stage(1, fbs[1]);
    stage(2, fbs[2]);
    stage(3, fbs[3]);

#pragma unroll
    for (int tc = 0; tc < 8; ++tc) {
        // own chunk-tc loads done; chunks tc+1..tc+3 (2 gld16 each) in flight
        if      (tc <= 4) asm volatile("s_waitcnt vmcnt(6)" ::: "memory");
        else if (tc == 5) asm volatile("s_waitcnt vmcnt(4)" ::: "memory");
        else if (tc == 6) asm volatile("s_waitcnt vmcnt(2)" ::: "memory");
        else              asm volatile("s_waitcnt vmcnt(0)" ::: "memory");
        PIPE_OPEN();                       // cross-wave staging visible; reads pinned below

        short* buf = fbs[tc & 3];
#pragma unroll
        for (int jb = 0; jb < 2; ++jb) {       // 32 j per step
            short8 bfr[4];
#pragma unroll
            for (int nf = 0; nf < 4; ++nf) {
                int col = nf * 16 + l15;
                bfr[nf] = *(const short8*)(buf + col * 64 + (((jb * 4 + quad) ^ (col & 7)) << 3));
            }
            int o = tc * 64 + jb * 32 + quad * 8;
            f32x4 pa = *(const f32x4*)(p2_s + o), pb = *(const f32x4*)(p2_s + o + 4);
            f32x4 qa = *(const f32x4*)(q2_s + o), qb = *(const f32x4*)(q2_s + o + 4);
            float p2v[8] = {pa[0], pa[1], pa[2], pa[3], pb[0], pb[1], pb[2], pb[3]};
            float q2v[8] = {qa[0], qa[1], qa[2], qa[3], qb[0], qb[1], qb[2], qb[3]};

            __builtin_amdgcn_s_setprio(1);     // T5: favor E-pack->MFMA waves
#pragma unroll
            for (int rt = 0; rt < 2; ++rt) {   // E-frag in A-layout: m=l15, k=quad*8+t
                const float R = Rr[rt];
                short8 ef;
#pragma unroll
                for (int t = 0; t < 8; ++t)
                    ef[t] = f2bf_rn(fmaxf(p2v[t], R * q2v[t]));
                for (int nf = 0; nf < 4; ++nf)
                    acc[rt][nf] = __builtin_amdgcn_mfma_f32_16x16x32_bf16(ef, bfr[nf], acc[rt][nf], 0, 0, 0);
                accL[rt] = __builtin_amdgcn_mfma_f32_16x16x32_bf16(ef, onesv, accL[rt], 0, 0, 0);
            }
            __builtin_amdgcn_s_setprio(0);
        }

        PIPE_CLOSE();                      // reads drained; safe to restage
        if (tc + 4 < 8) stage(tc + 4, fbs[tc & 3]);
    }

    // ---- epilogue: normalize (L already per-row in C-layout), residual, ELU, store
    for (int rt = 0; rt < 2; ++rt) {
        float rinv[4];
        for (int r = 0; r < 4; ++r) rinv[r] = __builtin_amdgcn_rcpf(accL[rt][r]);
        int i0 = r0 + w * 32 + rt * 16 + quad * 4;
        for (int nf = 0; nf < 4; ++nf) {
            int col = nf * 16 + l15;
            ushort4 res = *(const ushort4*)(fts + fbase + col * 512 + i0);
            unsigned short rr[4] = {res.x, res.y, res.z, res.w};
            for (int r = 0; r < 4; ++r) {
                float val = acc[rt][nf][r] * rinv[r] + bf2f((short)rr[r]);
                if (val < 0.f) val = __builtin_amdgcn_exp2f(val * L2E) - 1.f;  // elu
                size_t oidx = (size_t)(b * 512 + i0 + r) * 512 + h * 64 + col;
                if constexpr (sizeof(OutT) == 4) out[oidx] = val;
                else                             out[oidx] = f2bf(val);
            }
        }
    }
}

// ---------------------------------------------------------------------------
extern "C" void kernel_launch(void* const* d_in, const int* in_sizes, int n_in,
                              void* d_out, int out_size, void* d_ws, size_t ws_size,
                              hipStream_t stream) {
    const float* x   = (const float*)d_in[0];   // (32,512,128) f32
    const float* W0  = (const float*)d_in[1];   // (8,128,64)
    const float* W1  = (const float*)d_in[2];   // (8,512,64)
    const float* a1w = (const float*)d_in[3];   // (2,8,64)
    const float* a1b = (const float*)d_in[4];   // (2,8)
    const float* a2w = (const float*)d_in[5];   // (2,8,64)
    const float* a2b = (const float*)d_in[6];   // (2,8)
    float* out = (float*)d_out;                 // (32,512,512) f32

    char* ws = (char*)d_ws;
    short* BT0  = (short*)(ws);                 // 512x128 bf16   (131072 B)
    short* BT1  = (short*)(ws + 131072);        // 512x512 bf16   (524288 B)
    float* fbuf = (float*)(ws + 655360);        // 4 x 131072 f32 (2097152 B)
    short* fts  = (short*)(ws + 2752512);       // (8,32,64,512) bf16 (16.78 MB)
    short* hbuf = (short*)d_out;                // bf16 hidden in d_out (overwritten later)

    wtrans_kernel<<<1280, 256, 0, stream>>>(W0, W1, BT0, BT1);

    // stack 0
    gemm_kernel<float><<<512, 256, 0, stream>>>(x, BT0, fts, 128,
                                                a1w, a1b, a2w, a2b, fbuf);
    attn_kernel<short><<<1024, 256, 0, stream>>>(fts, fbuf, hbuf);

    // stack 1
    gemm_kernel<short><<<512, 256, 0, stream>>>(hbuf, BT1, fts, 512,
                                                a1w + 512, a1b + 8, a2w + 512, a2b + 8, fbuf);
    attn_kernel<float><<<1024, 256, 0, stream>>>(fts, fbuf, out);
}

// Round 10
// 144.157 us; speedup vs baseline: 1.0157x; 1.0106x over previous
//
#include <hip/hip_runtime.h>
#include <hip/hip_bf16.h>
#include <stdint.h>

typedef __attribute__((ext_vector_type(8))) short short8;
typedef __attribute__((ext_vector_type(4))) float f32x4;

#define L2E 1.44269504f
#define FN  131072              // elements per f-array: H*B*N = 8*32*512

__device__ __forceinline__ short f2bf(float f) {
    unsigned u = __builtin_bit_cast(unsigned, f);
    return (short)((u + 0x8000u) >> 16);   // round-half-up to bf16
}
__device__ __forceinline__ short f2bf_rn(float f) {    // compiler RNE cast
    __hip_bfloat16 h = __float2bfloat16(f);            // -> v_cvt_pk_bf16_f32
    return __builtin_bit_cast(short, h);
}
__device__ __forceinline__ float bf2f(short s) {
    unsigned u = ((unsigned)(unsigned short)s) << 16;
    return __builtin_bit_cast(float, u);
}

// async global->LDS, 16B per lane; LDS dest = wave-uniform base + lane*16
__device__ __forceinline__ void gld16(void* l, const void* g) {
    __builtin_amdgcn_global_load_lds(
        (const __attribute__((address_space(1))) unsigned*)g,
        (__attribute__((address_space(3))) unsigned*)l, 16, 0, 0);
}

// Hardened pipeline sync helpers (raw s_barrier does NOT order memory):
//  PIPE_OPEN : after the vmcnt-wait + barrier, pin all reads BELOW the
//              barrier (cross-wave staging only guaranteed complete there).
//  PIPE_CLOSE: drain own LDS reads (lgkmcnt) and pin them ABOVE the barrier
//              before any wave restages into the buffer just read.
#define PIPE_OPEN()  do { __builtin_amdgcn_s_barrier();                        \
                          __builtin_amdgcn_sched_barrier(0);                   \
                          asm volatile("" ::: "memory"); } while (0)
#define PIPE_CLOSE() do { asm volatile("s_waitcnt lgkmcnt(0)" ::: "memory");   \
                          __builtin_amdgcn_sched_barrier(0);                   \
                          __builtin_amdgcn_s_barrier(); } while (0)

// ---------------------------------------------------------------------------
// Kernel 1: transpose + fp32->bf16 convert W -> BT.
// Round 10: LDS tile-transpose. Old version wrote 64 lanes x 2B at 256B
// stride (64 L2 sectors per wave-store). Now: 64x64 tiles, coalesced global
// read (256B/wave), f32 LDS with +1 pad (2-way max banks), coalesced bf16
// write (128B/wave). 80 tiles: W0 = 8h x 2 ktiles, W1 = 8h x 8 ktiles.
// ---------------------------------------------------------------------------
__global__ __launch_bounds__(256)
void wtrans_kernel(const float* __restrict__ W0, const float* __restrict__ W1,
                   short* __restrict__ BT0, short* __restrict__ BT1) {
    __shared__ float sm[64][65];
    const int t    = blockIdx.x;
    const int lane = threadIdx.x & 63;
    const int r4   = threadIdx.x >> 6;     // 0..3

    const float* src;
    short* dst;
    int k0, ldk;
    if (t < 16) {                          // W0: (8,128,64) -> BT0 (8*64,128)
        int h = t >> 1; k0 = (t & 1) * 64;
        src = W0 + h * 8192;  dst = BT0 + h * 64 * 128;  ldk = 128;
    } else {                               // W1: (8,512,64) -> BT1 (8*64,512)
        int u = t - 16;
        int h = u >> 3; k0 = (u & 7) * 64;
        src = W1 + (size_t)h * 32768;  dst = BT1 + (size_t)h * 64 * 512;  ldk = 512;
    }

#pragma unroll
    for (int i = 0; i < 16; ++i) {         // load 64 rows (k), 4/iter, coalesced
        int r = i * 4 + r4;
        sm[r][lane] = src[(k0 + r) * 64 + lane];
    }
    __syncthreads();
#pragma unroll
    for (int i = 0; i < 16; ++i) {         // write 64 rows (dd), coalesced in k
        int dd = i * 4 + r4;
        dst[dd * ldk + k0 + lane] = f2bf(sm[lane][dd]);
    }
}

// ---------------------------------------------------------------------------
// Kernel 2: GEMM  C(16384 x 512) = A(16384 x K) @ BT(512 x K)^T, bf16 MFMA.
// 1D grid, XCD-aware decode; bf16-A path pipelined (counted vmcnt + hardened
// barriers); fp32-A path legacy __syncthreads. (unchanged from round 4/7)
// ---------------------------------------------------------------------------
template <typename AT>
__global__ __launch_bounds__(256, 2)
void gemm_kernel(const AT* __restrict__ A, const short* __restrict__ BT,
                 short* __restrict__ fts, int K,
                 const float* __restrict__ a1w, const float* __restrict__ a1b,
                 const float* __restrict__ a2w, const float* __restrict__ a2b,
                 float* __restrict__ fbuf) {
    __shared__ __align__(16) short As[2][128 * 64];   // 32 KB
    __shared__ __align__(16) short Bs[2][128 * 64];   // 32 KB

    const int tid  = threadIdx.x;
    const int lane = tid & 63;
    const int w    = tid >> 6;
    const int wr   = w >> 1, wc = w & 1;
    const int quad = lane >> 4, l15 = lane & 15;

    // XCD-aware decode: id bits [8:5]=g, [4:3]=k(n-block), [2:0]=x.
    // by = g*8+x; same-by blocks differ by 8 -> same XCD. Bijective.
    const int id = blockIdx.x;
    const int bx = (id >> 3) & 3;
    const int by = ((id >> 5) << 3) + (id & 7);
    const int m0 = by * 128;
    const int n0 = bx * 128;

    // async-staging lane map: 8 rows x 8 chunks per instr
    const int rl   = lane >> 3;        // row_local 0..7
    const int cpos = lane & 7;         // physical LDS chunk
    const int kcl  = cpos ^ rl;        // global chunk to fetch ((row&7)==rl)

    f32x4 acc[4][4];
    for (int i = 0; i < 4; ++i)
        for (int j = 0; j < 4; ++j) { f32x4 z = {0.f, 0.f, 0.f, 0.f}; acc[i][j] = z; }

    const int nkb = K >> 6;

    if constexpr (sizeof(AT) == 4) {
        // ---------------- legacy loop: fp32 A (K=128, 2 k-steps) ----------
        for (int kb = 0; kb < nkb; ++kb) {
            __syncthreads();
            for (int i = 0; i < 8; ++i) {      // fp32 A: manual convert-staging
                int id2 = tid + i * 256;
                int row = id2 >> 4, q = id2 & 15;  // q: 4-float subchunk
                int c = q >> 1, half = q & 1;
                float4 v = *(const float4*)((const float*)A + (size_t)(m0 + row) * K + kb * 64 + q * 4);
                ushort4 p;
                p.x = (unsigned short)f2bf(v.x);
                p.y = (unsigned short)f2bf(v.y);
                p.z = (unsigned short)f2bf(v.z);
                p.w = (unsigned short)f2bf(v.w);
                int swz = c ^ (row & 7);
                *(ushort4*)(As[0] + row * 64 + swz * 8 + half * 4) = p;
            }
            for (int i = 0; i < 4; ++i) {      // B bf16 async
                int rowb = w * 32 + i * 8;
                gld16(Bs[0] + rowb * 64,
                      BT + (size_t)(n0 + rowb + rl) * K + kb * 64 + kcl * 8);
            }
            __syncthreads();
            short8 af[2][4], bf[2][4];
            for (int ks = 0; ks < 2; ++ks) {
                for (int mf = 0; mf < 4; ++mf) {
                    int row = wr * 64 + mf * 16 + l15;
                    af[ks][mf] = *(const short8*)(As[0] + row * 64 + (((ks * 4 + quad) ^ (row & 7)) << 3));
                }
                for (int nf = 0; nf < 4; ++nf) {
                    int row = wc * 64 + nf * 16 + l15;
                    bf[ks][nf] = *(const short8*)(Bs[0] + row * 64 + (((ks * 4 + quad) ^ (row & 7)) << 3));
                }
            }
            for (int ks = 0; ks < 2; ++ks)
                for (int mf = 0; mf < 4; ++mf)
                    for (int nf = 0; nf < 4; ++nf)
                        acc[mf][nf] = __builtin_amdgcn_mfma_f32_16x16x32_bf16(af[ks][mf], bf[ks][nf], acc[mf][nf], 0, 0, 0);
        }
    } else {
        // ---------------- pipelined loop: bf16 A (K=512, 8 k-steps) -------
        auto stageAB = [&](int kb, int bufi) {
#pragma unroll
            for (int i = 0; i < 4; ++i) {
                int rowb = w * 32 + i * 8;
                gld16(As[bufi] + rowb * 64,
                      (const short*)A + (size_t)(m0 + rowb + rl) * K + kb * 64 + kcl * 8);
            }
#pragma unroll
            for (int i = 0; i < 4; ++i) {
                int rowb = w * 32 + i * 8;
                gld16(Bs[bufi] + rowb * 64,
                      BT + (size_t)(n0 + rowb + rl) * K + kb * 64 + kcl * 8);
            }
        };
        stageAB(0, 0);
        if (nkb > 1) stageAB(1, 1);
        for (int kb = 0; kb < nkb; ++kb) {
            // own stage(kb) done; stage(kb+1)'s 8 gld16 stay in flight
            if (kb + 1 < nkb) asm volatile("s_waitcnt vmcnt(8)" ::: "memory");
            else              asm volatile("s_waitcnt vmcnt(0)" ::: "memory");
            PIPE_OPEN();                     // all waves' stage(kb) done; reads pinned below
            const short* as = As[kb & 1];
            const short* bs = Bs[kb & 1];
            short8 af[2][4], bf[2][4];
            for (int ks = 0; ks < 2; ++ks) {
                for (int mf = 0; mf < 4; ++mf) {
                    int row = wr * 64 + mf * 16 + l15;
                    af[ks][mf] = *(const short8*)(as + row * 64 + (((ks * 4 + quad) ^ (row & 7)) << 3));
                }
                for (int nf = 0; nf < 4; ++nf) {
                    int row = wc * 64 + nf * 16 + l15;
                    bf[ks][nf] = *(const short8*)(bs + row * 64 + (((ks * 4 + quad) ^ (row & 7)) << 3));
                }
            }
            for (int ks = 0; ks < 2; ++ks)
                for (int mf = 0; mf < 4; ++mf)
                    for (int nf = 0; nf < 4; ++nf)
                        acc[mf][nf] = __builtin_amdgcn_mfma_f32_16x16x32_bf16(af[ks][mf], bf[ks][nf], acc[mf][nf], 0, 0, 0);
            PIPE_CLOSE();                    // reads drained; safe to restage
            if (kb + 2 < nkb) stageAB(kb + 2, kb & 1);
        }
    }

    // ---- epilogue A: transposed fts store
    for (int nf = 0; nf < 4; ++nf) {
        int col = n0 + wc * 64 + nf * 16 + l15;
        int h = col >> 6, dd = col & 63;
        for (int mf = 0; mf < 4; ++mf) {
            int m = m0 + wr * 64 + mf * 16 + quad * 4;
            int b = m >> 9, n = m & 511;
            ushort4 pk;
            pk.x = (unsigned short)f2bf(acc[mf][nf][0]);
            pk.y = (unsigned short)f2bf(acc[mf][nf][1]);
            pk.z = (unsigned short)f2bf(acc[mf][nf][2]);
            pk.w = (unsigned short)f2bf(acc[mf][nf][3]);
            *(ushort4*)(fts + (size_t)((h * 32 + b) * 64 + dd) * 512 + n) = pk;
        }
    }

    // ---- epilogue B: P/Q exp factors from fp32 acc. head = n0/64 + wc.
    {
        const int head = (n0 >> 6) + wc;
        float w1[4], w2[4];
        for (int nf = 0; nf < 4; ++nf) {
            w1[nf] = a1w[head * 64 + nf * 16 + l15];
            w2[nf] = a2w[head * 64 + nf * 16 + l15];
        }
        const float b1 = a1b[head], b2 = a2b[head];
        const int rsel = l15 & 3;
        for (int mf = 0; mf < 4; ++mf) {
            float g1[4], g2[4];
            for (int r = 0; r < 4; ++r) {
                float s1 = 0.f, s2 = 0.f;
                for (int nf = 0; nf < 4; ++nf) {
                    s1 += acc[mf][nf][r] * w1[nf];
                    s2 += acc[mf][nf][r] * w2[nf];
                }
                for (int m = 1; m < 16; m <<= 1) {
                    s1 += __shfl_xor(s1, m, 64);
                    s2 += __shfl_xor(s2, m, 64);
                }
                g1[r] = s1; g2[r] = s2;
            }
            float v1 = rsel == 0 ? g1[0] : rsel == 1 ? g1[1] : rsel == 2 ? g1[2] : g1[3];
            float v2 = rsel == 0 ? g2[0] : rsel == 1 ? g2[1] : rsel == 2 ? g2[2] : g2[3];
            if (l15 < 4) {
                int m = m0 + wr * 64 + mf * 16 + quad * 4 + rsel;
                int b = m >> 9, i = m & 511;
                int fi = (head * 32 + b) * 512 + i;
                float f1 = v1 + b1, f2 = v2 + b2;
                fbuf[0 * FN + fi] = __builtin_amdgcn_exp2f(f1 * L2E);
                fbuf[1 * FN + fi] = __builtin_amdgcn_exp2f(f1 * (0.01f * L2E));
                fbuf[2 * FN + fi] = __builtin_amdgcn_exp2f(f2 * L2E);
                fbuf[3 * FN + fi] = __builtin_amdgcn_exp2f(f2 * (0.01f * L2E));
            }
        }
    }
}

// ---------------------------------------------------------------------------
// Kernel 3: fused GAT attention. One block = (h, b, 128-row quarter).
//   e~(i,j) = max(P2_j, R_i*Q2_j), R_i=Q1_i/P1_i (row-scale invariant form)
//   O[i,:] = sum_j e~ * fts[j,:];  L[i] = sum_j e~;  out = elu(O/L + fts[i,:])
// Base = round 7 (best, 144.70): 8x8KB chunks, 4-buffer ring, depth-3
// prefetch, counted vmcnt + hardened barriers, thin E-pack. R9's setprio
// reverted (neutral). Round 10 change: nontemporal store for the f32 output
// (write-once, never re-read -> don't displace fts/fbuf in L2). hbuf (bf16)
// stays cached: gemm1 re-reads it immediately.
// ---------------------------------------------------------------------------
template <typename OutT>
__global__ __launch_bounds__(256, 4)
void attn_kernel(const short* __restrict__ fts, const float* __restrict__ fbuf,
                 OutT* __restrict__ out) {
    __shared__ __align__(16) short fbs[4][64 * 64];  // 4 x 8KB chunk ring
    __shared__ __align__(16) float p2_s[512];        // 2 KB
    __shared__ __align__(16) float q2_s[512];        // 2 KB

    const int tid  = threadIdx.x;
    const int lane = tid & 63, w = tid >> 6;
    const int quad = lane >> 4, l15 = lane & 15;
    const int bx   = blockIdx.x;
    const int quarter = bx >> 8;           // 0..3
    const int slab = bx & 255;             // h*32+b, same-XCD for all 4 quarters
    const int h    = slab >> 5;
    const int b    = slab & 31;
    const int r0   = quarter * 128;
    const size_t fbase = (size_t)(slab * 64) * 512;
    const int fidx = slab * 512;

    // staging lane map: each gld16 covers 8 d-rows x 8 slots of 16B (64 n)
    const int srow = lane >> 3;            // d-row within instr group 0..7
    const int spc  = lane & 7;             // physical LDS 16B slot

    f32x4 acc[2][4], accL[2];
    for (int i = 0; i < 2; ++i) {
        f32x4 z = {0.f, 0.f, 0.f, 0.f};
        accL[i] = z;
        for (int j = 0; j < 4; ++j) acc[i][j] = z;
    }
    short8 onesv;
    for (int t = 0; t < 8; ++t) onesv[t] = (short)0x3F80;   // bf16 1.0

    float Rr[2];                           // R_i = Q1_i / P1_i per rt
    for (int rt = 0; rt < 2; ++rt) {
        int i = fidx + r0 + w * 32 + rt * 16 + l15;
        float P1 = fbuf[i];
        float Q1 = fbuf[1 * FN + i];
        Rr[rt] = Q1 * __builtin_amdgcn_rcpf(P1);
    }

    const float* p2g = fbuf + 2 * FN + fidx;
    const float* q2g = fbuf + 3 * FN + fidx;

    // ---- issue p/q staging (1 gld16 per wave -> uniform vmcnt counts)
    if (w < 2) gld16(p2_s + w * 256, p2g + w * 256 + lane * 4);
    else       gld16(q2_s + (w - 2) * 256, q2g + (w - 2) * 256 + lane * 4);

    // ---- chunk staging: 2 gld16/thread-wave covers 16 d-rows x 64 n.
    //      LDS slot spc holds global 16B-chunk spc^(d&7) (source pre-swizzle,
    //      LDS linear; reads apply the same XOR).
    auto stage = [&](int tc, short* buf) {
#pragma unroll
        for (int i = 0; i < 2; ++i) {
            int d0 = w * 16 + i * 8;       // multiple of 8 -> d&7 == srow
            int d  = d0 + srow;
            gld16(buf + d0 * 64,
                  fts + fbase + (size_t)d * 512 + tc * 64 + ((spc ^ srow) << 3));
        }
    };
    stage(0, fbs[0]);
    stage(1, fbs[1]);
    stage(2, fbs[2]);
    stage(3, fbs[3]);

#pragma unroll
    for (int tc = 0; tc < 8; ++tc) {
        // own chunk-tc loads done; chunks tc+1..tc+3 (2 gld16 each) in flight
        if      (tc <= 4) asm volatile("s_waitcnt vmcnt(6)" ::: "memory");
        else if (tc == 5) asm volatile("s_waitcnt vmcnt(4)" ::: "memory");
        else if (tc == 6) asm volatile("s_waitcnt vmcnt(2)" ::: "memory");
        else              asm volatile("s_waitcnt vmcnt(0)" ::: "memory");
        PIPE_OPEN();                       // cross-wave staging visible; reads pinned below

        short* buf = fbs[tc & 3];
#pragma unroll
        for (int jb = 0; jb < 2; ++jb) {       // 32 j per step
            short8 bfr[4];
#pragma unroll
            for (int nf = 0; nf < 4; ++nf) {
                int col = nf * 16 + l15;
                bfr[nf] = *(const short8*)(buf + col * 64 + (((jb * 4 + quad) ^ (col & 7)) << 3));
            }
            int o = tc * 64 + jb * 32 + quad * 8;
            f32x4 pa = *(const f32x4*)(p2_s + o), pb = *(const f32x4*)(p2_s + o + 4);
            f32x4 qa = *(const f32x4*)(q2_s + o), qb = *(const f32x4*)(q2_s + o + 4);
            float p2v[8] = {pa[0], pa[1], pa[2], pa[3], pb[0], pb[1], pb[2], pb[3]};
            float q2v[8] = {qa[0], qa[1], qa[2], qa[3], qb[0], qb[1], qb[2], qb[3]};

#pragma unroll
            for (int rt = 0; rt < 2; ++rt) {   // E-frag in A-layout: m=l15, k=quad*8+t
                const float R = Rr[rt];
                short8 ef;
#pragma unroll
                for (int t = 0; t < 8; ++t)
                    ef[t] = f2bf_rn(fmaxf(p2v[t], R * q2v[t]));
                for (int nf = 0; nf < 4; ++nf)
                    acc[rt][nf] = __builtin_amdgcn_mfma_f32_16x16x32_bf16(ef, bfr[nf], acc[rt][nf], 0, 0, 0);
                accL[rt] = __builtin_amdgcn_mfma_f32_16x16x32_bf16(ef, onesv, accL[rt], 0, 0, 0);
            }
        }

        PIPE_CLOSE();                      // reads drained; safe to restage
        if (tc + 4 < 8) stage(tc + 4, fbs[tc & 3]);
    }

    // ---- epilogue: normalize (L already per-row in C-layout), residual, ELU, store
    for (int rt = 0; rt < 2; ++rt) {
        float rinv[4];
        for (int r = 0; r < 4; ++r) rinv[r] = __builtin_amdgcn_rcpf(accL[rt][r]);
        int i0 = r0 + w * 32 + rt * 16 + quad * 4;
        for (int nf = 0; nf < 4; ++nf) {
            int col = nf * 16 + l15;
            ushort4 res = *(const ushort4*)(fts + fbase + col * 512 + i0);
            unsigned short rr[4] = {res.x, res.y, res.z, res.w};
            for (int r = 0; r < 4; ++r) {
                float val = acc[rt][nf][r] * rinv[r] + bf2f((short)rr[r]);
                if (val < 0.f) val = __builtin_amdgcn_exp2f(val * L2E) - 1.f;  // elu
                size_t oidx = (size_t)(b * 512 + i0 + r) * 512 + h * 64 + col;
                if constexpr (sizeof(OutT) == 4)
                    __builtin_nontemporal_store(val, &out[oidx]);  // write-once f32
                else
                    out[oidx] = f2bf(val);                         // hbuf: keep cached
            }
        }
    }
}

// ---------------------------------------------------------------------------
extern "C" void kernel_launch(void* const* d_in, const int* in_sizes, int n_in,
                              void* d_out, int out_size, void* d_ws, size_t ws_size,
                              hipStream_t stream) {
    const float* x   = (const float*)d_in[0];   // (32,512,128) f32
    const float* W0  = (const float*)d_in[1];   // (8,128,64)
    const float* W1  = (const float*)d_in[2];   // (8,512,64)
    const float* a1w = (const float*)d_in[3];   // (2,8,64)
    const float* a1b = (const float*)d_in[4];   // (2,8)
    const float* a2w = (const float*)d_in[5];   // (2,8,64)
    const float* a2b = (const float*)d_in[6];   // (2,8)
    float* out = (float*)d_out;                 // (32,512,512) f32

    char* ws = (char*)d_ws;
    short* BT0  = (short*)(ws);                 // 512x128 bf16   (131072 B)
    short* BT1  = (short*)(ws + 131072);        // 512x512 bf16   (524288 B)
    float* fbuf = (float*)(ws + 655360);        // 4 x 131072 f32 (2097152 B)
    short* fts  = (short*)(ws + 2752512);       // (8,32,64,512) bf16 (16.78 MB)
    short* hbuf = (short*)d_out;                // bf16 hidden in d_out (overwritten later)

    wtrans_kernel<<<80, 256, 0, stream>>>(W0, W1, BT0, BT1);

    // stack 0
    gemm_kernel<float><<<512, 256, 0, stream>>>(x, BT0, fts, 128,
                                                a1w, a1b, a2w, a2b, fbuf);
    attn_kernel<short><<<1024, 256, 0, stream>>>(fts, fbuf, hbuf);

    // stack 1
    gemm_kernel<short><<<512, 256, 0, stream>>>(hbuf, BT1, fts, 512,
                                                a1w + 512, a1b + 8, a2w + 512, a2b + 8, fbuf);
    attn_kernel<float><<<1024, 256, 0, stream>>>(fts, fbuf, out);
}